// Round 26
// baseline (286.827 us; speedup 1.0000x reference)
//
#include <hip/hip_runtime.h>
#include <cstdint>
#include <cstddef>

#define M_DIM 8192
#define N_DIM 4096
#define K_DIM 4096

typedef _Float16 f16x8 __attribute__((ext_vector_type(8)));
typedef float f32x16 __attribute__((ext_vector_type(16)));
typedef float f32x4 __attribute__((ext_vector_type(4)));
typedef unsigned short ushort8 __attribute__((ext_vector_type(8)));

#define GLOAD_LDS16(g, l)                                                      \
  __builtin_amdgcn_global_load_lds(                                            \
      (const __attribute__((address_space(1))) void*)(g),                      \
      (__attribute__((address_space(3))) void*)(l), 16, 0, 0)

// code c in {0,1,2} -> fp16 bits of (c-1)
__device__ inline uint32_t lutf16(uint32_t c) {
  return (c == 1u) ? 0u : (0x3C00u | ((uint32_t)(c == 0u) << 15));
}

// ---- prep: X f32 [M,K] -> f16 [M,K] in ws (exact: values fp16-origin) ----
__global__ __launch_bounds__(256) void prep_x(const float4* __restrict__ X,
                                              ushort8* __restrict__ Xf) {
  int i = blockIdx.x * 256 + threadIdx.x;
  float4 f0 = X[2 * (size_t)i], f1 = X[2 * (size_t)i + 1];
  ushort8 us;
  us[0] = __builtin_bit_cast(uint16_t, (_Float16)f0.x);
  us[1] = __builtin_bit_cast(uint16_t, (_Float16)f0.y);
  us[2] = __builtin_bit_cast(uint16_t, (_Float16)f0.z);
  us[3] = __builtin_bit_cast(uint16_t, (_Float16)f0.w);
  us[4] = __builtin_bit_cast(uint16_t, (_Float16)f1.x);
  us[5] = __builtin_bit_cast(uint16_t, (_Float16)f1.y);
  us[6] = __builtin_bit_cast(uint16_t, (_Float16)f1.z);
  us[7] = __builtin_bit_cast(uint16_t, (_Float16)f1.w);
  Xf[i] = us;
}

// ---- prep: W int32 [N,K/4] (1 byte/word) -> f16 [N,K] in ws ----
__global__ __launch_bounds__(256) void prep_w(const uint2* __restrict__ W,
                                              uint4* __restrict__ Wf) {
  int i = blockIdx.x * 256 + threadIdx.x;
  uint2 wv = W[(size_t)i];
  uint32_t x = wv.x & 0xFFu, y = wv.y & 0xFFu;
  uint4 o;
  o.x = lutf16(x & 3u) | (lutf16((x >> 2) & 3u) << 16);
  o.y = lutf16((x >> 4) & 3u) | (lutf16((x >> 6) & 3u) << 16);
  o.z = lutf16(y & 3u) | (lutf16((y >> 2) & 3u) << 16);
  o.w = lutf16((y >> 4) & 3u) | (lutf16((y >> 6) & 3u) << 16);
  Wf[i] = o;
}

// ---- 256x256 GEMM with 32x32x16 MFMA + R21 cross-barrier read-ahead ----
// R26 vs R21: MFMA shape 16x16x32 -> 32x32x16 (ubench 2382 vs 2075 TF,
// half the MFMA instructions) and 4 barriers/K-tile instead of 8, keeping
// the PROVEN read-ahead (every fragment consumed >=1 barrier after issue).
// Per wave: 4 M-blocks x 2 N-blocks of 32x32, acc[4][2] f32x16 = 128 AGPR.
// Groups g0..g3 per K-tile: (mbp=g>>1, kh=g&1) = 2 mb x 2 nb x 2 ks =
// 8 MFMA, 4 independent acc chains (ks-outer). A-frag: row=lane&31,
// k=(lane>>5)*8+j (16B/lane); C/D: col=lane&31, row=(reg&3)+8*(reg>>2)+
// 4*(lane>>5) (m74/m101 verified). Bank-uniform with existing XOR swizzle.
// Liveness/wait tables (per pair, 8 phases): stages B(t+2)@ph1/2,
// A(t+2)@ph4/5, B(t+3)@ph6/7, A(t+3)@ph8x2; VM4@ph3 (A(t+1),B(t+1) landed),
// VM4@ph7 (A(t+2),B(t+2) landed); every stage >=1 barrier after its slot's
// last read. No setprio (R23: -22%).
__global__ __launch_bounds__(512, 2) void gemm8(
    const _Float16* __restrict__ A,  // [M,K] f16 (ws)
    const _Float16* __restrict__ B,  // [N,K] f16 (ws)
    const float* __restrict__ G,     // gamma f32
    float* __restrict__ C) {         // [M,N] f32
  __shared__ __align__(16) _Float16 As[2][16384];
  __shared__ __align__(16) _Float16 Bs[2][16384];

  const int tid = threadIdx.x;
  const int wid = tid >> 6;
  const int lane = tid & 63;
  const int wr = wid >> 2;   // 0..1  (M half)
  const int wcq = wid & 3;   // 0..3  (N quarter)
  const int l31 = lane & 31, lh = lane >> 5;

  int bid = (int)blockIdx.x;
  int swz = ((bid & 7) << 6) | (bid >> 3);  // 512 blocks, bijective
  const int bm = (swz >> 4) * 256;
  const int bn = (swz & 15) * 256;

  const int sr8 = lane >> 3;
  const int scol = ((lane & 7) ^ sr8) * 8;  // pre-swizzled source chunk

  f32x16 acc[4][2] = {};
  f16x8 bfr[2][4];
  f16x8 afA[2][2], afB[2][2];

#define STAGE(t, ht)                                                           \
  do {                                                                         \
    const int buf_ = (t) & 1;                                                  \
    const int kt_ = (t) << 6;                                                  \
    const _Float16* src_ =                                                     \
        ((ht) < 2) ? (B + (size_t)bn * K_DIM) : (A + (size_t)bm * K_DIM);      \
    _Float16* dst_ = ((ht) < 2) ? Bs[buf_] : As[buf_];                         \
    const int h_ = (ht) & 1;                                                   \
    _Pragma("unroll") for (int j_ = 0; j_ < 2; ++j_) {                         \
      int sg_ = h_ * 16 + wid * 2 + j_;                                        \
      int row_ = sg_ * 8 + sr8;                                                \
      GLOAD_LDS16(src_ + (size_t)row_ * K_DIM + kt_ + scol, dst_ + sg_ * 512); \
    }                                                                          \
  } while (0)

#define READ_B(t)                                                              \
  do {                                                                         \
    const int buf_ = (t) & 1;                                                  \
    _Pragma("unroll") for (int nb_ = 0; nb_ < 2; ++nb_) {                      \
      int row_ = wcq * 64 + nb_ * 32 + l31;                                    \
      _Pragma("unroll") for (int ks_ = 0; ks_ < 4; ++ks_) {                    \
        int ch_ = ks_ * 2 + lh;                                                \
        bfr[nb_][ks_] = *reinterpret_cast<const f16x8*>(                       \
            Bs[buf_] + row_ * 64 + (((ch_) ^ (row_ & 7)) * 8));                \
      }                                                                        \
    }                                                                          \
  } while (0)

#define READ_A_G(t, g, dst)                                                    \
  do {                                                                         \
    const int buf_ = (t) & 1;                                                  \
    const int mbp_ = (g) >> 1, kh_ = (g) & 1;                                  \
    _Pragma("unroll") for (int i_ = 0; i_ < 2; ++i_) {                         \
      int row_ = wr * 128 + (mbp_ * 2 + i_) * 32 + l31;                        \
      _Pragma("unroll") for (int j_ = 0; j_ < 2; ++j_) {                       \
        int ch_ = (kh_ * 2 + j_) * 2 + lh;                                     \
        dst[i_][j_] = *reinterpret_cast<const f16x8*>(                         \
            As[buf_] + row_ * 64 + (((ch_) ^ (row_ & 7)) * 8));                \
      }                                                                        \
    }                                                                          \
  } while (0)

#define MFMA_G(g, src)                                                         \
  do {                                                                         \
    const int mbp_ = (g) >> 1, kh_ = (g) & 1;                                  \
    _Pragma("unroll") for (int j_ = 0; j_ < 2; ++j_)                           \
      _Pragma("unroll") for (int i_ = 0; i_ < 2; ++i_)                         \
        _Pragma("unroll") for (int nb_ = 0; nb_ < 2; ++nb_)                    \
          acc[mbp_ * 2 + i_][nb_] = __builtin_amdgcn_mfma_f32_32x32x16_f16(    \
              src[i_][j_], bfr[nb_][kh_ * 2 + j_], acc[mbp_ * 2 + i_][nb_],    \
              0, 0, 0);                                                        \
  } while (0)

#define BAR() __builtin_amdgcn_s_barrier()
#define VM4() asm volatile("s_waitcnt vmcnt(4)" ::: "memory")
#define VM0() asm volatile("s_waitcnt vmcnt(0)" ::: "memory")

  // prologue: tiles 0,1 fully staged; drain; prime bfr(0) + A(0,g0).
  STAGE(0, 0); STAGE(0, 1); STAGE(0, 2); STAGE(0, 3);
  STAGE(1, 0); STAGE(1, 1); STAGE(1, 2); STAGE(1, 3);
  VM0();
  BAR();
  READ_B(0);
  READ_A_G(0, 0, afA);

  for (int i = 0; i < 31; ++i) {
    const int t = 2 * i;
    // ph1
    READ_A_G(t, 1, afB); STAGE(t + 2, 0);
    MFMA_G(0, afA); BAR();
    // ph2
    READ_A_G(t, 2, afA); STAGE(t + 2, 1);
    MFMA_G(1, afB); BAR();
    // ph3: VM4 -> A(t+1)@prev-ph8 + B(t+1)@prev-ph6/7 landed (leaves ph1/2)
    READ_A_G(t, 3, afB);
    MFMA_G(2, afA); VM4(); BAR();
    // ph4: A(t) slots free (last read ph3) -> stage A(t+2).lo
    READ_A_G(t + 1, 0, afA); STAGE(t + 2, 2);
    MFMA_G(3, afB); READ_B(t + 1); BAR();
    // ph5
    READ_A_G(t + 1, 1, afB); STAGE(t + 2, 3);
    MFMA_G(0, afA); BAR();
    // ph6: B(t+1) slots free (LDS-read ph4) -> stage B(t+3)
    READ_A_G(t + 1, 2, afA); STAGE(t + 3, 0);
    MFMA_G(1, afB); BAR();
    // ph7: VM4 -> A(t+2)@ph4/5 + B(t+2)@ph1/2 landed (leaves ph6/7)
    READ_A_G(t + 1, 3, afB); STAGE(t + 3, 1);
    MFMA_G(2, afA); VM4(); BAR();
    // ph8: A(t+1) slots free (last read ph7) -> stage A(t+3) both halves
    READ_A_G(t + 2, 0, afA); STAGE(t + 3, 2); STAGE(t + 3, 3);
    MFMA_G(3, afB); READ_B(t + 2); BAR();
  }
  // peeled pair (62,63): no further staging
  READ_A_G(62, 1, afB); MFMA_G(0, afA); BAR();
  READ_A_G(62, 2, afA); MFMA_G(1, afB); BAR();
  READ_A_G(62, 3, afB); MFMA_G(2, afA); VM0(); BAR();
  READ_A_G(63, 0, afA); MFMA_G(3, afB); READ_B(63); BAR();
  READ_A_G(63, 1, afB); MFMA_G(0, afA); BAR();
  READ_A_G(63, 2, afA); MFMA_G(1, afB); BAR();
  READ_A_G(63, 3, afB); MFMA_G(2, afA); BAR();
  MFMA_G(3, afB);

  float g = G[0];
  if (!(__builtin_fabsf(g) >= 0.001f && __builtin_fabsf(g) <= 1000.0f)) g = 1.0f;
#pragma unroll
  for (int mb = 0; mb < 4; ++mb)
#pragma unroll
    for (int nb = 0; nb < 2; ++nb) {
      int col = bn + wcq * 64 + nb * 32 + l31;
      int rowbase = bm + wr * 128 + mb * 32 + 4 * lh;
#pragma unroll
      for (int reg = 0; reg < 16; ++reg) {
        int row = rowbase + (reg & 3) + 8 * (reg >> 2);
        C[(size_t)row * N_DIM + col] = acc[mb][nb][reg] * g;
      }
    }
#undef STAGE
#undef READ_B
#undef READ_A_G
#undef MFMA_G
#undef BAR
#undef VM4
#undef VM0
}

// ---- fallback GEMM (ws too small): inline cvt/decode, XOR-swizzled LDS ----
__global__ __launch_bounds__(256) void gemm_inline(
    const float* __restrict__ X, const uint32_t* __restrict__ W,
    const float* __restrict__ G, float* __restrict__ C) {
  __shared__ __align__(16) _Float16 As[128 * 64];
  __shared__ __align__(16) _Float16 Bs[128 * 64];

  const int tid = threadIdx.x;
  const int wave = tid >> 6;
  const int lane = tid & 63;
  const int wr = wave >> 1, wc = wave & 1;
  const int fr = lane & 15, kg = lane >> 4;
  const int bm = blockIdx.y * 128, bn = blockIdx.x * 128;
  const int brow = tid >> 1, bhalf = tid & 1;

  f32x4 acc[4][4] = {};

  for (int kt = 0; kt < K_DIM; kt += 64) {
#pragma unroll
    for (int i = 0; i < 4; ++i) {
      int c = i * 256 + tid;
      int row = c >> 3, cc = c & 7;
      const float4* p =
          (const float4*)(X + (size_t)(bm + row) * K_DIM + kt + cc * 8);
      float4 f0 = p[0], f1 = p[1];
      ushort8 us;
      us[0] = __builtin_bit_cast(uint16_t, (_Float16)f0.x);
      us[1] = __builtin_bit_cast(uint16_t, (_Float16)f0.y);
      us[2] = __builtin_bit_cast(uint16_t, (_Float16)f0.z);
      us[3] = __builtin_bit_cast(uint16_t, (_Float16)f0.w);
      us[4] = __builtin_bit_cast(uint16_t, (_Float16)f1.x);
      us[5] = __builtin_bit_cast(uint16_t, (_Float16)f1.y);
      us[6] = __builtin_bit_cast(uint16_t, (_Float16)f1.z);
      us[7] = __builtin_bit_cast(uint16_t, (_Float16)f1.w);
      *reinterpret_cast<ushort8*>((uint16_t*)As + row * 64 +
                                  (cc ^ (row & 7)) * 8) = us;
    }
    {
      const uint32_t* wp =
          W + (size_t)(bn + brow) * 1024 + (kt >> 2) + bhalf * 8;
      uint32_t w[8];
      *(uint4*)(w) = *(const uint4*)(wp);
      *(uint4*)(w + 4) = *(const uint4*)(wp + 4);
#pragma unroll
      for (int q = 0; q < 4; ++q) {
        uint32_t x = w[2 * q] & 0xFFu, y = w[2 * q + 1] & 0xFFu;
        uint4 o;
        o.x = lutf16(x & 3u) | (lutf16((x >> 2) & 3u) << 16);
        o.y = lutf16((x >> 4) & 3u) | (lutf16((x >> 6) & 3u) << 16);
        o.z = lutf16(y & 3u) | (lutf16((y >> 2) & 3u) << 16);
        o.w = lutf16((y >> 4) & 3u) | (lutf16((y >> 6) & 3u) << 16);
        int slot = (bhalf * 4 + q) ^ (brow & 7);
        *reinterpret_cast<uint4*>((uint16_t*)Bs + brow * 64 + slot * 8) = o;
      }
    }
    __syncthreads();

#pragma unroll
    for (int ks = 0; ks < 2; ++ks) {
      f16x8 a[4], b[4];
#pragma unroll
      for (int r = 0; r < 4; ++r) {
        int row = wr * 64 + r * 16 + fr;
        a[r] = *reinterpret_cast<const f16x8*>(
            As + row * 64 + ((ks * 4 + kg) ^ (row & 7)) * 8);
      }
#pragma unroll
      for (int c = 0; c < 4; ++c) {
        int row = wc * 64 + c * 16 + fr;
        b[c] = *reinterpret_cast<const f16x8*>(
            Bs + row * 64 + ((ks * 4 + kg) ^ (row & 7)) * 8);
      }
#pragma unroll
      for (int r = 0; r < 4; ++r)
#pragma unroll
        for (int c = 0; c < 4; ++c)
          acc[r][c] = __builtin_amdgcn_mfma_f32_16x16x32_f16(a[r], b[c],
                                                             acc[r][c], 0, 0, 0);
    }
    __syncthreads();
  }

  float g = G[0];
  if (!(__builtin_fabsf(g) >= 0.001f && __builtin_fabsf(g) <= 1000.0f)) g = 1.0f;
#pragma unroll
  for (int r = 0; r < 4; ++r)
#pragma unroll
    for (int c = 0; c < 4; ++c) {
      int col = bn + wc * 64 + c * 16 + fr;
      int row0 = bm + wr * 64 + r * 16 + kg * 4;
#pragma unroll
      for (int j = 0; j < 4; ++j)
        C[(size_t)(row0 + j) * N_DIM + col] = acc[r][c][j] * g;
    }
}

extern "C" void kernel_launch(void* const* d_in, const int* in_sizes, int n_in,
                              void* d_out, int out_size, void* d_ws,
                              size_t ws_size, hipStream_t stream) {
  const float* x = (const float*)d_in[0];
  const uint32_t* w32 = (const uint32_t*)d_in[1];
  const float* gamma = (const float*)d_in[2];
  float* out = (float*)d_out;
  (void)in_sizes; (void)n_in; (void)out_size;

  const size_t xf_bytes = (size_t)M_DIM * K_DIM * 2;  // 67.1 MB
  const size_t wf_bytes = (size_t)N_DIM * K_DIM * 2;  // 33.6 MB

  if (ws_size >= xf_bytes + wf_bytes) {
    _Float16* xf = (_Float16*)d_ws;
    _Float16* wf = (_Float16*)((char*)d_ws + xf_bytes);
    prep_x<<<M_DIM * K_DIM / 8 / 256, 256, 0, stream>>>((const float4*)x,
                                                        (ushort8*)xf);
    prep_w<<<N_DIM * K_DIM / 8 / 256, 256, 0, stream>>>((const uint2*)w32,
                                                        (uint4*)wf);
    gemm8<<<(M_DIM / 256) * (N_DIM / 256), 512, 0, stream>>>(xf, wf, gamma,
                                                             out);
  } else {
    dim3 grid(N_DIM / 128, M_DIM / 128);
    gemm_inline<<<grid, 256, 0, stream>>>(x, w32, gamma, out);
  }
}

// Round 27
// 256.222 us; speedup vs baseline: 1.1194x; 1.1194x over previous
//
#include <hip/hip_runtime.h>
#include <cstdint>
#include <cstddef>

#define M_DIM 8192
#define N_DIM 4096
#define K_DIM 4096

typedef _Float16 f16x8 __attribute__((ext_vector_type(8)));
typedef float f32x4 __attribute__((ext_vector_type(4)));
typedef unsigned short ushort8 __attribute__((ext_vector_type(8)));

#define GLOAD_LDS16(g, l)                                                      \
  __builtin_amdgcn_global_load_lds(                                            \
      (const __attribute__((address_space(1))) void*)(g),                      \
      (__attribute__((address_space(3))) void*)(l), 16, 0, 0)

// code c in {0,1,2} -> fp16 bits of (c-1)
__device__ inline uint32_t lutf16(uint32_t c) {
  return (c == 1u) ? 0u : (0x3C00u | ((uint32_t)(c == 0u) << 15));
}

// ---- fused prep: X f32->f16 (blocks [0,16384)) + W int32->f16 (rest) ----
// Independent memory-bound passes fused into one launch so they overlap.
__global__ __launch_bounds__(256) void prep_fused(
    const float4* __restrict__ X, ushort8* __restrict__ Xf,
    const uint2* __restrict__ W, uint4* __restrict__ Wf) {
  int b = blockIdx.x;
  if (b < M_DIM * K_DIM / 8 / 256) {
    int i = b * 256 + threadIdx.x;
    float4 f0 = X[2 * (size_t)i], f1 = X[2 * (size_t)i + 1];
    ushort8 us;
    us[0] = __builtin_bit_cast(uint16_t, (_Float16)f0.x);
    us[1] = __builtin_bit_cast(uint16_t, (_Float16)f0.y);
    us[2] = __builtin_bit_cast(uint16_t, (_Float16)f0.z);
    us[3] = __builtin_bit_cast(uint16_t, (_Float16)f0.w);
    us[4] = __builtin_bit_cast(uint16_t, (_Float16)f1.x);
    us[5] = __builtin_bit_cast(uint16_t, (_Float16)f1.y);
    us[6] = __builtin_bit_cast(uint16_t, (_Float16)f1.z);
    us[7] = __builtin_bit_cast(uint16_t, (_Float16)f1.w);
    Xf[i] = us;
  } else {
    int i = (b - M_DIM * K_DIM / 8 / 256) * 256 + threadIdx.x;
    uint2 wv = W[(size_t)i];
    uint32_t x = wv.x & 0xFFu, y = wv.y & 0xFFu;
    uint4 o;
    o.x = lutf16(x & 3u) | (lutf16((x >> 2) & 3u) << 16);
    o.y = lutf16((x >> 4) & 3u) | (lutf16((x >> 6) & 3u) << 16);
    o.z = lutf16(y & 3u) | (lutf16((y >> 2) & 3u) << 16);
    o.w = lutf16((y >> 4) & 3u) | (lutf16((y >> 6) & 3u) << 16);
    Wf[i] = o;
  }
}

// ---- 256x256 8-phase GEMM, cross-barrier read-ahead (BEST: R21) ----
// Final kernel: R21 (247us GEMM, 1114 TF, MfmaUtil 48%, 0 bank conflicts).
// Each phase's MFMA cluster consumes A-quad fragments loaded the PREVIOUS
// phase (afA/afB ping-pong); B(t+1) read in ph4/ph8 after last bfr(t) use.
// Race-free rotation (stage >=1 barrier after the slot's last read):
// ph1:(t+1,2),(t+1,3) ph2:(t+2,0) ph3:(t+2,1) ph4:- ph5:(t+2,2) ph6:(t+2,3)
// ph7:(t+3,0) ph8:(t+3,1). Collective waits (vmcnt BEFORE phase-end
// barrier): VM4@ph3 (tile t+1 landed), VM2@ph7 (tile t+2 landed).
// Measured-negative alternatives: setprio (-22% R23), phase-merge (-13%
// R22), 32x32 MFMA (-13% R26, bank conflicts), 2-block/CU (R24,
// VGPR-impossible), B-from-L2 (-45% R14).
__global__ __launch_bounds__(512, 2) void gemm8(
    const _Float16* __restrict__ A,  // [M,K] f16 (ws)
    const _Float16* __restrict__ B,  // [N,K] f16 (ws)
    const float* __restrict__ G,     // gamma f32
    float* __restrict__ C) {         // [M,N] f32
  __shared__ __align__(16) _Float16 As[2][16384];
  __shared__ __align__(16) _Float16 Bs[2][16384];

  const int tid = threadIdx.x;
  const int wid = tid >> 6;
  const int lane = tid & 63;
  const int wr = wid >> 2;   // 0..1  (M half)
  const int wcq = wid & 3;   // 0..3  (N quarter)
  const int fr = lane & 15, kg = lane >> 4;

  int bid = (int)blockIdx.x;
  int swz = ((bid & 7) << 6) | (bid >> 3);  // 512 blocks, bijective
  const int bm = (swz >> 4) * 256;
  const int bn = (swz & 15) * 256;

  const int sr8 = lane >> 3;
  const int scol = ((lane & 7) ^ sr8) * 8;  // pre-swizzled source chunk

  f32x4 acc[8][4] = {};
  f16x8 bfr[4][2];
  f16x8 afA[2][2], afB[2][2];

#define STAGE(t, ht)                                                           \
  do {                                                                         \
    const int buf_ = (t) & 1;                                                  \
    const int kt_ = (t) << 6;                                                  \
    const _Float16* src_ =                                                     \
        ((ht) < 2) ? (B + (size_t)bn * K_DIM) : (A + (size_t)bm * K_DIM);      \
    _Float16* dst_ = ((ht) < 2) ? Bs[buf_] : As[buf_];                         \
    const int h_ = (ht) & 1;                                                   \
    _Pragma("unroll") for (int j_ = 0; j_ < 2; ++j_) {                         \
      int sg_ = h_ * 16 + wid * 2 + j_;                                        \
      int row_ = sg_ * 8 + sr8;                                                \
      GLOAD_LDS16(src_ + (size_t)row_ * K_DIM + kt_ + scol, dst_ + sg_ * 512); \
    }                                                                          \
  } while (0)

#define READ_B(t)                                                              \
  do {                                                                         \
    const int buf_ = (t) & 1;                                                  \
    _Pragma("unroll") for (int ni_ = 0; ni_ < 4; ++ni_)                        \
        _Pragma("unroll") for (int ks_ = 0; ks_ < 2; ++ks_) {                  \
      int row_ = wcq * 64 + ni_ * 16 + fr;                                     \
      bfr[ni_][ks_] = *reinterpret_cast<const f16x8*>(                         \
          Bs[buf_] + row_ * 64 + (((ks_ * 4 + kg) ^ (row_ & 7)) * 8));         \
    }                                                                          \
  } while (0)

#define READ_A(t, q, dst)                                                      \
  do {                                                                         \
    const int buf_ = (t) & 1;                                                  \
    _Pragma("unroll") for (int m2_ = 0; m2_ < 2; ++m2_)                        \
        _Pragma("unroll") for (int ks_ = 0; ks_ < 2; ++ks_) {                  \
      int row_ = wr * 128 + ((q) * 2 + m2_) * 16 + fr;                         \
      dst[m2_][ks_] = *reinterpret_cast<const f16x8*>(                         \
          As[buf_] + row_ * 64 + (((ks_ * 4 + kg) ^ (row_ & 7)) * 8));         \
    }                                                                          \
  } while (0)

#define MFMA_Q(q, src)                                                         \
  do {                                                                         \
    _Pragma("unroll") for (int ks_ = 0; ks_ < 2; ++ks_)                        \
        _Pragma("unroll") for (int m2_ = 0; m2_ < 2; ++m2_)                    \
            _Pragma("unroll") for (int ni_ = 0; ni_ < 4; ++ni_)                \
                acc[(q) * 2 + m2_][ni_] =                                      \
        __builtin_amdgcn_mfma_f32_16x16x32_f16(                                \
            src[m2_][ks_], bfr[ni_][ks_], acc[(q) * 2 + m2_][ni_], 0, 0, 0);   \
  } while (0)

#define BAR() __builtin_amdgcn_s_barrier()
#define VM4() asm volatile("s_waitcnt vmcnt(4)" ::: "memory")
#define VM2() asm volatile("s_waitcnt vmcnt(2)" ::: "memory")
#define VM0() asm volatile("s_waitcnt vmcnt(0)" ::: "memory")

  // prologue: tile0 fully + B of tile1; VM4 -> tile0 landed (leaves
  // (1,0),(1,1) in flight = steady-state pattern); BAR; prime bfr + afA.
  STAGE(0, 0); STAGE(0, 1); STAGE(0, 2); STAGE(0, 3);
  STAGE(1, 0); STAGE(1, 1);
  VM4();
  BAR();
  READ_B(0);
  READ_A(0, 0, afA);

  for (int i = 0; i < 31; ++i) {
    const int t = 2 * i;
    // ph1: read q1 ahead; MFMA q0 (loaded prev phase)
    READ_A(t, 1, afB); STAGE(t + 1, 2); STAGE(t + 1, 3);
    MFMA_Q(0, afA); BAR();
    // ph2
    READ_A(t, 2, afA); STAGE(t + 2, 0);
    MFMA_Q(1, afB); BAR();
    // ph3: VM4 before barrier -> A(t+1)@ph1 + B(t+1)@prev ph7/8 landed
    READ_A(t, 3, afB); STAGE(t + 2, 1);
    MFMA_Q(2, afA); VM4(); BAR();
    // ph4: read next tile's q0; B(t+1) re-read AFTER last bfr(t) use
    READ_A(t + 1, 0, afA);
    MFMA_Q(3, afB); READ_B(t + 1); BAR();
    // ph5
    READ_A(t + 1, 1, afB); STAGE(t + 2, 2);
    MFMA_Q(0, afA); BAR();
    // ph6
    READ_A(t + 1, 2, afA); STAGE(t + 2, 3);
    MFMA_Q(1, afB); BAR();
    // ph7: VM2 -> A(t+2)@ph5/6 + B(t+2)@ph2/3 landed (leaves ph7's 2)
    READ_A(t + 1, 3, afB); STAGE(t + 3, 0);
    MFMA_Q(2, afA); VM2(); BAR();
    // ph8
    READ_A(t + 2, 0, afA); STAGE(t + 3, 1);
    MFMA_Q(3, afB); READ_B(t + 2); BAR();
  }
  // peeled last pair t=62/63
  {
    const int t = 62;
    READ_A(t, 1, afB); STAGE(63, 2); STAGE(63, 3);
    MFMA_Q(0, afA); BAR();
    READ_A(t, 2, afA); MFMA_Q(1, afB); BAR();
    READ_A(t, 3, afB); MFMA_Q(2, afA); VM0(); BAR();
    READ_A(63, 0, afA); MFMA_Q(3, afB); READ_B(63); BAR();
    READ_A(63, 1, afB); MFMA_Q(0, afA); BAR();
    READ_A(63, 2, afA); MFMA_Q(1, afB); BAR();
    READ_A(63, 3, afB); MFMA_Q(2, afA); BAR();
    MFMA_Q(3, afB);
  }

  float g = G[0];
  if (!(__builtin_fabsf(g) >= 0.001f && __builtin_fabsf(g) <= 1000.0f)) g = 1.0f;
#pragma unroll
  for (int m = 0; m < 8; ++m)
#pragma unroll
    for (int ni = 0; ni < 4; ++ni) {
      int col = bn + wcq * 64 + ni * 16 + fr;
      int row0 = bm + wr * 128 + m * 16 + kg * 4;
#pragma unroll
      for (int j = 0; j < 4; ++j)
        C[(size_t)(row0 + j) * N_DIM + col] = acc[m][ni][j] * g;
    }
#undef STAGE
#undef READ_B
#undef READ_A
#undef MFMA_Q
#undef BAR
#undef VM4
#undef VM2
#undef VM0
}

// ---- fallback GEMM (ws too small): inline cvt/decode, XOR-swizzled LDS ----
__global__ __launch_bounds__(256) void gemm_inline(
    const float* __restrict__ X, const uint32_t* __restrict__ W,
    const float* __restrict__ G, float* __restrict__ C) {
  __shared__ __align__(16) _Float16 As[128 * 64];
  __shared__ __align__(16) _Float16 Bs[128 * 64];

  const int tid = threadIdx.x;
  const int wave = tid >> 6;
  const int lane = tid & 63;
  const int wr = wave >> 1, wc = wave & 1;
  const int fr = lane & 15, kg = lane >> 4;
  const int bm = blockIdx.y * 128, bn = blockIdx.x * 128;
  const int brow = tid >> 1, bhalf = tid & 1;

  f32x4 acc[4][4] = {};

  for (int kt = 0; kt < K_DIM; kt += 64) {
#pragma unroll
    for (int i = 0; i < 4; ++i) {
      int c = i * 256 + tid;
      int row = c >> 3, cc = c & 7;
      const float4* p =
          (const float4*)(X + (size_t)(bm + row) * K_DIM + kt + cc * 8);
      float4 f0 = p[0], f1 = p[1];
      ushort8 us;
      us[0] = __builtin_bit_cast(uint16_t, (_Float16)f0.x);
      us[1] = __builtin_bit_cast(uint16_t, (_Float16)f0.y);
      us[2] = __builtin_bit_cast(uint16_t, (_Float16)f0.z);
      us[3] = __builtin_bit_cast(uint16_t, (_Float16)f0.w);
      us[4] = __builtin_bit_cast(uint16_t, (_Float16)f1.x);
      us[5] = __builtin_bit_cast(uint16_t, (_Float16)f1.y);
      us[6] = __builtin_bit_cast(uint16_t, (_Float16)f1.z);
      us[7] = __builtin_bit_cast(uint16_t, (_Float16)f1.w);
      *reinterpret_cast<ushort8*>((uint16_t*)As + row * 64 +
                                  (cc ^ (row & 7)) * 8) = us;
    }
    {
      const uint32_t* wp =
          W + (size_t)(bn + brow) * 1024 + (kt >> 2) + bhalf * 8;
      uint32_t w[8];
      *(uint4*)(w) = *(const uint4*)(wp);
      *(uint4*)(w + 4) = *(const uint4*)(wp + 4);
#pragma unroll
      for (int q = 0; q < 4; ++q) {
        uint32_t x = w[2 * q] & 0xFFu, y = w[2 * q + 1] & 0xFFu;
        uint4 o;
        o.x = lutf16(x & 3u) | (lutf16((x >> 2) & 3u) << 16);
        o.y = lutf16((x >> 4) & 3u) | (lutf16((x >> 6) & 3u) << 16);
        o.z = lutf16(y & 3u) | (lutf16((y >> 2) & 3u) << 16);
        o.w = lutf16((y >> 4) & 3u) | (lutf16((y >> 6) & 3u) << 16);
        int slot = (bhalf * 4 + q) ^ (brow & 7);
        *reinterpret_cast<uint4*>((uint16_t*)Bs + brow * 64 + slot * 8) = o;
      }
    }
    __syncthreads();

#pragma unroll
    for (int ks = 0; ks < 2; ++ks) {
      f16x8 a[4], b[4];
#pragma unroll
      for (int r = 0; r < 4; ++r) {
        int row = wr * 64 + r * 16 + fr;
        a[r] = *reinterpret_cast<const f16x8*>(
            As + row * 64 + ((ks * 4 + kg) ^ (row & 7)) * 8);
      }
#pragma unroll
      for (int c = 0; c < 4; ++c) {
        int row = wc * 64 + c * 16 + fr;
        b[c] = *reinterpret_cast<const f16x8*>(
            Bs + row * 64 + ((ks * 4 + kg) ^ (row & 7)) * 8);
      }
#pragma unroll
      for (int r = 0; r < 4; ++r)
#pragma unroll
        for (int c = 0; c < 4; ++c)
          acc[r][c] = __builtin_amdgcn_mfma_f32_16x16x32_f16(a[r], b[c],
                                                             acc[r][c], 0, 0, 0);
    }
    __syncthreads();
  }

  float g = G[0];
  if (!(__builtin_fabsf(g) >= 0.001f && __builtin_fabsf(g) <= 1000.0f)) g = 1.0f;
#pragma unroll
  for (int r = 0; r < 4; ++r)
#pragma unroll
    for (int c = 0; c < 4; ++c) {
      int col = bn + wc * 64 + c * 16 + fr;
      int row0 = bm + wr * 64 + r * 16 + kg * 4;
#pragma unroll
      for (int j = 0; j < 4; ++j)
        C[(size_t)(row0 + j) * N_DIM + col] = acc[r][c][j] * g;
    }
}

extern "C" void kernel_launch(void* const* d_in, const int* in_sizes, int n_in,
                              void* d_out, int out_size, void* d_ws,
                              size_t ws_size, hipStream_t stream) {
  const float* x = (const float*)d_in[0];
  const uint32_t* w32 = (const uint32_t*)d_in[1];
  const float* gamma = (const float*)d_in[2];
  float* out = (float*)d_out;
  (void)in_sizes; (void)n_in; (void)out_size;

  const size_t xf_bytes = (size_t)M_DIM * K_DIM * 2;  // 67.1 MB
  const size_t wf_bytes = (size_t)N_DIM * K_DIM * 2;  // 33.6 MB

  if (ws_size >= xf_bytes + wf_bytes) {
    _Float16* xf = (_Float16*)d_ws;
    _Float16* wf = (_Float16*)((char*)d_ws + xf_bytes);
    int nx = M_DIM * K_DIM / 8 / 256;
    int nw = N_DIM * K_DIM / 8 / 256;
    prep_fused<<<nx + nw, 256, 0, stream>>>((const float4*)x, (ushort8*)xf,
                                            (const uint2*)w32, (uint4*)wf);
    gemm8<<<(M_DIM / 256) * (N_DIM / 256), 512, 0, stream>>>(xf, wf, gamma,
                                                             out);
  } else {
    dim3 grid(N_DIM / 128, M_DIM / 128);
    gemm_inline<<<grid, 256, 0, stream>>>(x, w32, gamma, out);
  }
}